// Round 4
// baseline (261.485 us; speedup 1.0000x reference)
//
#include <hip/hip_runtime.h>

#define V 50257
#define BROWS 256
#define HISTN 200
#define NT 1024
#define NB1 4096
#define CSTRIDE ((V + 3) >> 2)
#define SHIFT 32.0f

typedef unsigned int u32;

// Monotone key: ascending key order == ascending float order (finite floats only).
__device__ __forceinline__ u32 f2key(float s) {
  u32 u = __float_as_uint(s);
  return (u & 0x80000000u) ? ~u : (u | 0x80000000u);
}
__device__ __forceinline__ float key2f(u32 k) {
  u32 u = (k & 0x80000000u) ? (k ^ 0x80000000u) : ~k;
  return __uint_as_float(u);
}
// Fixed-shift unnormalized softmax weight; shift cancels in all normalized uses.
// |scaled logit| <~ 52 here: exp(s-32) spans normal floats for all kept mass.
__device__ __forceinline__ float wexp(u32 k) {
  return expf(key2f(k) - SHIFT);
}

// ---- exact count-order-statistic crossing over an LDS histogram ----
// Finds bin containing the target-th element in priority order
// (asc==0: from highest bin; asc==1: from lowest). out[0]=bin, out[1]=count before.
__device__ void crossCnt(const u32* h, int n, u32 target, int asc,
                         u32* spc, u32 tid, u32* out) {
  int C = (n + NT - 1) / NT;
  int d0 = (int)tid * C;
  u32 local = 0;
  for (int j = 0; j < C; ++j) {
    int d = d0 + j;
    if (d < n) local += h[asc ? d : (n - 1 - d)];
  }
  spc[tid] = local;
  __syncthreads();
  for (int off = 1; off < NT; off <<= 1) {
    u32 v = spc[tid];
    if ((int)tid >= off) v += spc[tid - off];
    __syncthreads();
    spc[tid] = v;
    __syncthreads();
  }
  u32 excl = (tid == 0) ? 0u : spc[tid - 1];
  u32 incl = spc[tid];
  if (excl < target && target <= incl) {   // exact (integer) -> unique claimant
    u32 acc = excl;
    for (int j = 0; j < C; ++j) {
      int d = d0 + j;
      if (d >= n) break;
      u32 b = asc ? (u32)d : (u32)(n - 1 - d);
      u32 c = h[b];
      if (target <= acc + c) { out[0] = b; out[1] = acc; break; }
      acc += c;
    }
  }
  __syncthreads();
}

// ---- weight-mass crossing: first bin (descending) where cumulative weight
// first exceeds P (absolute, with running base). Float association between the
// block scan and per-chunk sequential sums can hide a boundary crossing; threads
// whose prefix already exceeds P claim their first nonempty bin so the crossing
// is never lost. atomicMin picks the earliest claim.
// s_u[0]=found, s_u[1]=bin, s_f[0]=mass before bin (clamped to P).
__device__ void crossWt(const float* h, int n, int active, float P, float base,
                        float* spw, u32* s_u, float* s_f, u32 tid) {
  int C = (n + NT - 1) / NT;
  int d0 = (int)tid * C;
  if (tid == 0) { s_u[0] = 0u; s_u[2] = 0xFFFFFFFFu; }
  float local = 0.f;
  for (int j = 0; j < C; ++j) {
    int d = d0 + j;
    if (d < n) local += h[n - 1 - d];
  }
  spw[tid] = local;
  __syncthreads();
  for (int off = 1; off < NT; off <<= 1) {
    float v = spw[tid];
    if ((int)tid >= off) v += spw[tid - off];
    __syncthreads();
    spw[tid] = v;
    __syncthreads();
  }
  float excl = (tid == 0) ? 0.f : spw[tid - 1];
  u32 myfound = 0xFFFFFFFFu;
  float myb = 0.f;
  if (active) {
    float acc = base + excl;
    if (acc <= P) {
      for (int j = 0; j < C; ++j) {
        int d = d0 + j;
        if (d >= n) break;
        float w = h[n - 1 - d];
        if (acc <= P && acc + w > P) { myfound = (u32)d; myb = acc; break; }
        acc += w;
      }
    } else {
      // prefix already beyond P: rounding hid the crossing upstream of this
      // chunk -> claim first nonempty bin (boundary-accurate within rounding).
      for (int j = 0; j < C; ++j) {
        int d = d0 + j;
        if (d >= n) break;
        if (h[n - 1 - d] > 0.f) { myfound = (u32)d; myb = P; break; }
      }
    }
    if (myfound != 0xFFFFFFFFu) atomicMin(&s_u[2], myfound);
  }
  __syncthreads();
  if (myfound != 0xFFFFFFFFu && myfound == s_u[2]) {
    s_u[0] = 1u;
    s_u[1] = (u32)(n - 1 - (int)myfound);
    s_f[0] = myb;
  }
  __syncthreads();
}

__device__ float blockSumW(const float* h, int n, float* spw, u32 tid) {
  float local = 0.f;
  for (int i = tid; i < n; i += NT) local += h[i];
  spw[tid] = local;
  __syncthreads();
  for (int off = NT / 2; off; off >>= 1) {
    if (tid < (u32)off) spw[tid] += spw[tid + off];
    __syncthreads();
  }
  float t = spw[0];
  __syncthreads();
  return t;
}

__global__ void __launch_bounds__(NT) sampler_main_kernel(
    const float* __restrict__ logits, const float* __restrict__ presp,
    const float* __restrict__ freqp, const float* __restrict__ tempp,
    const float* __restrict__ toppp, const int* __restrict__ toks,
    const int* __restrict__ topkp, u32* __restrict__ keys /* == d_out */) {
  const int row = blockIdx.x;
  const u32 tid = threadIdx.x;
  const size_t base = (size_t)row * V;
  const float fq = freqp[row], pr = presp[row], tmp = tempp[row], tp = toppp[row];
  int k_ = topkp[row];
  if (k_ < 1) k_ = 1;
  if (k_ > V) k_ = V;
  const u32 k = (u32)k_;

  __shared__ u32 sh_counts[CSTRIDE];   // 50260 B: packed byte-counts over vocab
  __shared__ u32 sh_cnt[NB1];
  __shared__ float sh_wt[NB1];
  __shared__ u32 sp_c[NT];
  __shared__ float sp_w[NT];
  __shared__ u32 s_u[4];
  __shared__ float s_f[2];
  __shared__ u32 s_k[2];

  // ---------- phase 0: per-row token counts in LDS ----------
  for (int i = tid; i < CSTRIDE; i += NT) sh_counts[i] = 0u;
  for (int i = tid; i < NB1; i += NT) { sh_cnt[i] = 0u; sh_wt[i] = 0.f; }
  __syncthreads();
  if (tid < HISTN) {
    int tok = toks[row * HISTN + tid];
    // 4 byte-counts per u32; max count 200 < 256 so no byte carry.
    atomicAdd(&sh_counts[tok >> 2], 1u << ((tok & 3) * 8));
  }
  __syncthreads();

  // ---------- phase 1: penalties + temp, keys to global, L1 histogram ----------
  for (int i = tid; i < V; i += NT) {
    float l = logits[base + i];
    u32 pc = sh_counts[i >> 2];
    u32 c = (pc >> ((i & 3) * 8)) & 0xFFu;
    float s = l - fq * (float)c;     // reference op order
    if (c) s -= pr;
    s = s / tmp;
    u32 key = f2key(s);
    keys[base + i] = key;
    atomicAdd(&sh_cnt[key >> 20], 1u);
    atomicAdd(&sh_wt[key >> 20], expf(s - SHIFT));
  }
  __syncthreads();

  // ---------- L1 crossings (12-bit bins) ----------
  float Z = blockSumW(sh_wt, NB1, sp_w, tid);
  float P = tp * Z;  // absolute (unnormalized) nucleus mass target
  crossCnt(sh_cnt, NB1, k, 0, sp_c, tid, s_k);
  u32 bk = s_k[0], cbk = s_k[1];
  crossWt(sh_wt, NB1, 1, P, 0.f, sp_w, s_u, s_f, tid);
  int pAct = (int)s_u[0];
  u32 bp = s_u[1];
  float wbp = s_f[0];
  u32 tauP = 0u;                 // default: top-p keeps everything
  u32 idxP = 0x7FFFFFFFu;
  __syncthreads();

  // ---------- L2 (next 12 bits) ----------
  for (int i = tid; i < NB1; i += NT) { sh_cnt[i] = 0u; sh_wt[i] = 0.f; }
  __syncthreads();
  for (int i = tid; i < V; i += NT) {
    u32 key = keys[base + i];
    u32 hi = key >> 20;
    if (hi == bk) atomicAdd(&sh_cnt[(key >> 8) & 0xFFFu], 1u);
    if (pAct && hi == bp) atomicAdd(&sh_wt[(key >> 8) & 0xFFFu], wexp(key));
  }
  __syncthreads();
  u32 tgt2 = k - cbk;
  crossCnt(sh_cnt, NB1, tgt2, 0, sp_c, tid, s_k);
  u32 bk2 = s_k[0], cbk2 = s_k[1];
  crossWt(sh_wt, NB1, pAct, P, wbp, sp_w, s_u, s_f, tid);
  int pAct2 = (int)s_u[0];
  u32 bp2 = s_u[1];
  float wbp2 = s_f[0];
  if (pAct && !pAct2) tauP = bp << 20;   // crossing at bin end within rounding:
                                         // keep whole L1 bin (mass err ~ rounding)
  __syncthreads();

  // ---------- L3 (last 8 bits): exact keys ----------
  for (int i = tid; i < 512; i += NT) sh_cnt[i] = 0u;
  for (int i = tid; i < 256; i += NT) sh_wt[i] = 0.f;
  __syncthreads();
  u32 prefK = (bk << 12) | bk2;
  u32 prefP = (bp << 12) | bp2;
  int pAct3 = pAct && pAct2;
  for (int i = tid; i < V; i += NT) {
    u32 key = keys[base + i];
    u32 hi = key >> 8;
    if (hi == prefK) atomicAdd(&sh_cnt[key & 0xFFu], 1u);
    if (pAct3 && hi == prefP) {
      atomicAdd(&sh_cnt[256 + (key & 0xFFu)], 1u);
      atomicAdd(&sh_wt[key & 0xFFu], wexp(key));
    }
  }
  __syncthreads();
  u32 tgt3 = tgt2 - cbk2;
  crossCnt(sh_cnt, 256, tgt3, 0, sp_c, tid, s_k);
  u32 bk3 = s_k[0], cbk3 = s_k[1];
  u32 tauK = (prefK << 8) | bk3;
  u32 cntEqK = sh_cnt[bk3];
  u32 tK = tgt3 - cbk3;               // kept ties for top-k, in [1, cntEqK]
  crossWt(sh_wt, 256, pAct3, P, wbp2, sp_w, s_u, s_f, tid);
  int pAct4 = (int)s_u[0];
  u32 bp3 = s_u[1];
  float wbp3 = s_f[0];
  u32 cntEqP = 0, tP = 0;
  if (pAct3 && !pAct4) tauP = prefP << 8;   // keep whole L2 sub-bin (rounding fallback)
  if (pAct3 && pAct4) {
    tauP = (prefP << 8) | bp3;
    cntEqP = sh_cnt[256 + bp3];
    float wt = wexp(tauP);              // equal-key ties share the same weight
    if (wt > 0.f) {
      float r = (P - wbp3) / wt;        // kept ties: excl = wbp3 + (t-1)*wt <= P
      if (r < 0.f) r = 0.f;
      if (r >= (float)cntEqP) tP = cntEqP;
      else {
        tP = (u32)r + 1u;
        if (tP > cntEqP) tP = cntEqP;
        if (tP < 1u) tP = 1u;
      }
    } else tP = cntEqP;
  }
  __syncthreads();

  // ---------- index tie-break selects (rare; exact stable-sort order) ----------
  u32 idxK = 0x7FFFFFFFu;
  if (tK < cntEqK) {
    for (int i = tid; i < 256; i += NT) sh_cnt[i] = 0u;
    __syncthreads();
    for (int i = tid; i < V; i += NT)
      if (keys[base + i] == tauK) atomicAdd(&sh_cnt[((u32)i) >> 8], 1u);
    __syncthreads();
    crossCnt(sh_cnt, 256, tK, 1, sp_c, tid, s_k);
    u32 bA = s_k[0], cbA = s_k[1];
    for (int i = tid; i < 256; i += NT) sh_cnt[i] = 0u;
    __syncthreads();
    for (int i = tid; i < V; i += NT)
      if (keys[base + i] == tauK && ((((u32)i) >> 8) == bA))
        atomicAdd(&sh_cnt[((u32)i) & 0xFFu], 1u);
    __syncthreads();
    crossCnt(sh_cnt, 256, tK - cbA, 1, sp_c, tid, s_k);
    idxK = (bA << 8) | s_k[0];
  }
  if (pAct3 && pAct4 && tP < cntEqP) {
    for (int i = tid; i < 256; i += NT) sh_cnt[i] = 0u;
    __syncthreads();
    for (int i = tid; i < V; i += NT)
      if (keys[base + i] == tauP) atomicAdd(&sh_cnt[((u32)i) >> 8], 1u);
    __syncthreads();
    crossCnt(sh_cnt, 256, tP, 1, sp_c, tid, s_k);
    u32 bA = s_k[0], cbA = s_k[1];
    for (int i = tid; i < 256; i += NT) sh_cnt[i] = 0u;
    __syncthreads();
    for (int i = tid; i < V; i += NT)
      if (keys[base + i] == tauP && ((((u32)i) >> 8) == bA))
        atomicAdd(&sh_cnt[((u32)i) & 0xFFu], 1u);
    __syncthreads();
    crossCnt(sh_cnt, 256, tP - cbA, 1, sp_c, tid, s_k);
    idxP = (bA << 8) | s_k[0];
  }

  // ---------- binding threshold = intersection of the two prefix sets ----------
  // Higher tau = more restrictive; equal tau -> smaller tie index wins.
  u32 tauS, idxS;
  if (tauK > tauP) { tauS = tauK; idxS = idxK; }
  else if (tauP > tauK) { tauS = tauP; idxS = idxP; }
  else { tauS = tauK; idxS = idxK < idxP ? idxK : idxP; }

  // ---------- final: masked weights -> Z_kept -> normalized probs ----------
  float zl = 0.f;
  float* outf = (float*)keys;
  for (int i = tid; i < V; i += NT) {
    u32 key = keys[base + i];
    bool kept = (key > tauS) || (key == tauS && (u32)i <= idxS);
    float w = kept ? wexp(key) : 0.f;
    outf[base + i] = w;
    zl += w;
  }
  sp_w[tid] = zl;
  __syncthreads();
  for (int off = NT / 2; off; off >>= 1) {
    if (tid < (u32)off) sp_w[tid] += sp_w[tid + off];
    __syncthreads();
  }
  float invZ = 1.0f / sp_w[0];
  for (int i = tid; i < V; i += NT) outf[base + i] *= invZ;
}

extern "C" void kernel_launch(void* const* d_in, const int* in_sizes, int n_in,
                              void* d_out, int out_size, void* d_ws, size_t ws_size,
                              hipStream_t stream) {
  const float* logits = (const float*)d_in[0];
  const float* presp  = (const float*)d_in[1];
  const float* freqp  = (const float*)d_in[2];
  const float* tempp  = (const float*)d_in[3];
  const float* toppp  = (const float*)d_in[4];
  const int*   toks   = (const int*)d_in[5];
  const int*   topkp  = (const int*)d_in[6];

  sampler_main_kernel<<<BROWS, NT, 0, stream>>>(logits, presp, freqp, tempp, toppp,
                                                toks, topkp, (u32*)d_out);
}

// Round 5
// 198.388 us; speedup vs baseline: 1.3181x; 1.3181x over previous
//
#include <hip/hip_runtime.h>

#define V 50257
#define BROWS 256
#define HISTN 200
#define NT 1024
#define NB1 4096
#define CAP 4096
#define CSTRIDE ((V + 3) >> 2)
#define SHIFT 32.0f
#define IDX_INF 0x7FFFFFFFu

typedef unsigned int u32;

// Monotone key: ascending key order == ascending float order (finite floats).
__device__ __forceinline__ u32 f2key(float s) {
  u32 u = __float_as_uint(s);
  return (u & 0x80000000u) ? ~u : (u | 0x80000000u);
}
__device__ __forceinline__ float key2f(u32 k) {
  u32 u = (k & 0x80000000u) ? (k ^ 0x80000000u) : ~k;
  return __uint_as_float(u);
}
// key2f(f2key(s)) is bit-exact, so wexp(key) == __expf(s-SHIFT) used in P1.
__device__ __forceinline__ float wexp(u32 k) {
  return __expf(key2f(k) - SHIFT);
}

// ---- shfl-based block scans/reduction (3 barriers each, not 20) ----
__device__ __forceinline__ u32 scanInclU(u32 v, u32* tmp, u32 tid) {
  __syncthreads();                      // protects tmp + callers' prior shared reads
#pragma unroll
  for (int d = 1; d < 64; d <<= 1) {
    u32 n = __shfl_up(v, d, 64);
    if ((int)(tid & 63) >= d) v += n;
  }
  if ((tid & 63) == 63) tmp[tid >> 6] = v;
  __syncthreads();
  if (tid < 16) {
    u32 w = tmp[tid];
#pragma unroll
    for (int d = 1; d < 16; d <<= 1) {
      u32 n = __shfl_up(w, d, 64);
      if ((int)tid >= d) w += n;
    }
    tmp[tid] = w;
  }
  __syncthreads();
  u32 wv = tid >> 6;
  return v + (wv ? tmp[wv - 1] : 0u);
}
__device__ __forceinline__ float scanInclF(float v, float* tmp, u32 tid) {
  __syncthreads();
#pragma unroll
  for (int d = 1; d < 64; d <<= 1) {
    float n = __shfl_up(v, d, 64);
    if ((int)(tid & 63) >= d) v += n;
  }
  if ((tid & 63) == 63) tmp[tid >> 6] = v;
  __syncthreads();
  if (tid < 16) {
    float w = tmp[tid];
#pragma unroll
    for (int d = 1; d < 16; d <<= 1) {
      float n = __shfl_up(w, d, 64);
      if ((int)tid >= d) w += n;
    }
    tmp[tid] = w;
  }
  __syncthreads();
  u32 wv = tid >> 6;
  return v + (wv ? tmp[wv - 1] : 0.f);
}
__device__ __forceinline__ float blockSumF(float v, float* tmp, u32 tid) {
  __syncthreads();
#pragma unroll
  for (int d = 32; d >= 1; d >>= 1) v += __shfl_xor(v, d, 64);
  if ((tid & 63) == 0) tmp[tid >> 6] = v;
  __syncthreads();
  if (tid == 0) {
    float s = 0.f;
#pragma unroll
    for (int w = 0; w < NT / 64; ++w) s += tmp[w];
    tmp[0] = s;
  }
  __syncthreads();
  return tmp[0];
}

// ---- exact count-order-statistic crossing (priority order; asc=1 from low) ----
// s_out[0]=bin, s_out[1]=count before. Requires 1 <= target <= total.
__device__ void crossCnt(const u32* h, int n, u32 target, int asc,
                         u32* tmp, u32* s_out, u32 tid) {
  int C = (n + NT - 1) / NT;
  int d0 = (int)tid * C;
  u32 local = 0;
  for (int j = 0; j < C; ++j) {
    int d = d0 + j;
    if (d < n) local += h[asc ? d : n - 1 - d];
  }
  u32 incl = scanInclU(local, tmp, tid);
  u32 excl = incl - local;
  if (excl < target && target <= incl) {   // exact integers -> unique claimant
    u32 acc = excl;
    for (int j = 0; j < C; ++j) {
      int d = d0 + j;
      if (d >= n) break;
      u32 b = asc ? (u32)d : (u32)(n - 1 - d);
      u32 c = h[b];
      if (target <= acc + c) { s_out[0] = b; s_out[1] = acc; break; }
      acc += c;
    }
  }
  __syncthreads();
}

// ---- weight-mass crossing, descending, absolute target P with base mass ----
// Threads whose scan-prefix already exceeds P claim their first nonempty bin so
// float association can never lose the crossing. s_u[0]=found, s_u[1]=bin,
// s_f[0]=absolute mass before bin (clamped to P on the rounding path).
__device__ void crossWt(const float* h, int n, float P, float base,
                        float* tmpf, u32* s_u, float* s_f, u32 tid) {
  __syncthreads();                       // callers finished reading prior results
  if (tid == 0) { s_u[0] = 0u; s_u[2] = 0xFFFFFFFFu; }
  int C = (n + NT - 1) / NT;
  int d0 = (int)tid * C;
  float local = 0.f;
  for (int j = 0; j < C; ++j) {
    int d = d0 + j;
    if (d < n) local += h[n - 1 - d];
  }
  float incl = scanInclF(local, tmpf, tid);
  float excl = incl - local;
  u32 myfound = 0xFFFFFFFFu;
  float myb = 0.f;
  float acc = base + excl;
  if (acc <= P) {
    for (int j = 0; j < C; ++j) {
      int d = d0 + j;
      if (d >= n) break;
      float w = h[n - 1 - d];
      if (acc + w > P) { myfound = (u32)d; myb = acc; break; }
      acc += w;
    }
  } else {
    for (int j = 0; j < C; ++j) {
      int d = d0 + j;
      if (d >= n) break;
      if (h[n - 1 - d] > 0.f) { myfound = (u32)d; myb = P; break; }
    }
  }
  if (myfound != 0xFFFFFFFFu) atomicMin(&s_u[2], myfound);
  __syncthreads();
  if (myfound != 0xFFFFFFFFu && myfound == s_u[2]) {
    s_u[0] = 1u; s_u[1] = (u32)(n - 1 - (int)myfound); s_f[0] = myb;
  }
  __syncthreads();
}

__global__ void __launch_bounds__(NT) sampler_main_kernel(
    const float* __restrict__ logits, const float* __restrict__ presp,
    const float* __restrict__ freqp, const float* __restrict__ tempp,
    const float* __restrict__ toppp, const int* __restrict__ toks,
    const int* __restrict__ topkp, u32* __restrict__ keys /* == d_out */) {
  const int row = blockIdx.x;
  const u32 tid = threadIdx.x;
  const size_t base = (size_t)row * V;
  const float fq = freqp[row], pr = presp[row], tmp_ = tempp[row], tp = toppp[row];
  int k_ = topkp[row];
  if (k_ < 1) k_ = 1;
  if (k_ > V) k_ = V;
  const u32 k = (u32)k_;

  __shared__ u32 sh_counts[CSTRIDE];   // 50260 B; dead after P1 -> candK overlay
  __shared__ u32 sh_ref[NB1];          // L1 cnt hist, then refinement hists
  __shared__ float sh_wt[NB1];         // L1 wt hist (persists for Z)
  __shared__ u32 candP_key[CAP];
  __shared__ u32 candP_idx[CAP];
  __shared__ u32 stmp[16];
  __shared__ float ftmp[16];
  __shared__ u32 s_res[4];
  __shared__ float s_fres[2];
  __shared__ u32 s_n[2];

  u32* candK_key = sh_counts;          // overlay: 2*CAP u32 = 32 KB <= 50.26 KB
  u32* candK_idx = sh_counts + CAP;

  // ---------- P1: token counts, keys, L1 histograms ----------
  for (int i = tid; i < CSTRIDE; i += NT) sh_counts[i] = 0u;
  for (int i = tid; i < NB1; i += NT) { sh_ref[i] = 0u; sh_wt[i] = 0.f; }
  __syncthreads();
  if (tid < HISTN) {
    int tok = toks[row * HISTN + (int)tid];
    atomicAdd(&sh_counts[tok >> 2], 1u << ((tok & 3) * 8));  // max count 200 < 256
  }
  __syncthreads();

  // (row*V) % 4 == row % 4 since V % 4 == 1 -> per-row 16B alignment offset
  const int i0 = (int)((4u - ((u32)row & 3u)) & 3u);
  const int Nv = (V - i0) >> 2;
  const int tail0 = i0 + Nv * 4;

  auto doElem = [&](int e) {
    float l = logits[base + e];
    u32 c = (sh_counts[e >> 2] >> ((e & 3) * 8)) & 0xFFu;
    float s = l - fq * (float)c;       // reference op order
    if (c) s -= pr;
    s = s / tmp_;
    u32 key = f2key(s);
    keys[base + e] = key;
    atomicAdd(&sh_ref[key >> 20], 1u);
    atomicAdd(&sh_wt[key >> 20], __expf(s - SHIFT));
  };
  if ((int)tid < i0) doElem((int)tid);
  if ((int)tid < V - tail0) doElem(tail0 + (int)tid);
  for (int j = (int)tid; j < Nv; j += NT) {
    int e = i0 + j * 4;
    const float4 L = *(const float4*)(logits + base + e);
    float ss[4] = {L.x, L.y, L.z, L.w};
    u32 kk[4];
#pragma unroll
    for (int l = 0; l < 4; ++l) {
      int ee = e + l;
      u32 c = (sh_counts[ee >> 2] >> ((ee & 3) * 8)) & 0xFFu;
      float s = ss[l] - fq * (float)c;
      if (c) s -= pr;
      s = s / tmp_;
      kk[l] = f2key(s);
      atomicAdd(&sh_ref[kk[l] >> 20], 1u);
      atomicAdd(&sh_wt[kk[l] >> 20], __expf(s - SHIFT));
    }
    *(uint4*)(keys + base + e) = make_uint4(kk[0], kk[1], kk[2], kk[3]);
  }
  __syncthreads();

  // ---------- L1 crossings ----------
  float zloc = 0.f;
  for (int i = tid; i < NB1; i += NT) zloc += sh_wt[i];
  const float Z = blockSumF(zloc, ftmp, tid);
  const float P = tp * Z;

  crossCnt(sh_ref, NB1, k, 0, stmp, s_res, tid);
  const u32 bk = s_res[0];
  const u32 cbk = s_res[1];
  crossWt(sh_wt, NB1, P, 0.f, ftmp, s_res, s_fres, tid);
  const int pAct = (int)s_res[0];
  const u32 bp = s_res[1];
  const float wbp = s_fres[0];

  // ---------- P2: compact candidates of the two L1 bins into LDS ----------
  if (tid == 0) { s_n[0] = 0u; s_n[1] = 0u; }
  __syncthreads();
  const int sepP = (pAct && bp != bk);
  auto compact = [&](int e, u32 key) {
    u32 hi = key >> 20;
    if (hi == bk) {
      u32 pos = atomicAdd(&s_n[0], 1u);
      if (pos < CAP) { candK_key[pos] = key; candK_idx[pos] = (u32)e; }
    } else if (sepP && hi == bp) {
      u32 pos = atomicAdd(&s_n[1], 1u);
      if (pos < CAP) { candP_key[pos] = key; candP_idx[pos] = (u32)e; }
    }
  };
  if ((int)tid < i0) compact((int)tid, keys[base + tid]);
  if ((int)tid < V - tail0) compact(tail0 + (int)tid, keys[base + tail0 + tid]);
  for (int j = (int)tid; j < Nv; j += NT) {
    int e = i0 + j * 4;
    uint4 K4 = *(const uint4*)(keys + base + e);
    compact(e, K4.x); compact(e + 1, K4.y);
    compact(e + 2, K4.z); compact(e + 3, K4.w);
  }
  __syncthreads();
  u32 nK = s_n[0]; if (nK > CAP) nK = CAP;   // max 12-bit-bin occupancy ~1.5K << CAP
  u32 nP = sepP ? s_n[1] : nK; if (nP > CAP) nP = CAP;
  const u32* cKk = candK_key; const u32* cKi = candK_idx;
  const u32* cPk = sepP ? candP_key : candK_key;
  const u32* cPi = sepP ? candP_idx : candK_idx;

  // ---------- top-k refinement (LDS-local) ----------
  u32 tgt = k - cbk;                      // rank within bin bk
  for (int i = tid; i < NB1; i += NT) sh_ref[i] = 0u;
  __syncthreads();
  for (u32 c = tid; c < nK; c += NT) atomicAdd(&sh_ref[(cKk[c] >> 8) & 0xFFFu], 1u);
  crossCnt(sh_ref, NB1, tgt, 0, stmp, s_res, tid);
  const u32 aK = s_res[0];
  tgt -= s_res[1];
  __syncthreads();
  for (int i = tid; i < 256; i += NT) sh_ref[i] = 0u;
  __syncthreads();
  for (u32 c = tid; c < nK; c += NT)
    if (((cKk[c] >> 8) & 0xFFFu) == aK) atomicAdd(&sh_ref[cKk[c] & 0xFFu], 1u);
  crossCnt(sh_ref, 256, tgt, 0, stmp, s_res, tid);
  const u32 bK3 = s_res[0];
  const u32 tauK = (bk << 20) | (aK << 8) | bK3;
  const u32 cntEqK = sh_ref[bK3];
  const u32 tK = tgt - s_res[1];          // kept ties in [1, cntEqK]

  u32 idxK = IDX_INF;
  if (tK < cntEqK) {                      // distinct random floats: ~never
    __syncthreads();
    for (int i = tid; i < 256; i += NT) sh_ref[i] = 0u;
    __syncthreads();
    for (u32 c = tid; c < nK; c += NT)
      if (cKk[c] == tauK) atomicAdd(&sh_ref[cKi[c] >> 8], 1u);
    crossCnt(sh_ref, 256, tK, 1, stmp, s_res, tid);
    u32 iA = s_res[0], ciA = s_res[1];
    __syncthreads();
    for (int i = tid; i < 256; i += NT) sh_ref[i] = 0u;
    __syncthreads();
    for (u32 c = tid; c < nK; c += NT)
      if (cKk[c] == tauK && (cKi[c] >> 8) == iA) atomicAdd(&sh_ref[cKi[c] & 0xFFu], 1u);
    crossCnt(sh_ref, 256, tK - ciA, 1, stmp, s_res, tid);
    idxK = (iA << 8) | s_res[0];
  }

  // ---------- top-p refinement (LDS-local) ----------
  u32 tauP = 0u;                          // default: top-p keeps everything
  u32 idxP = IDX_INF;
  if (pAct) {
    float* fh = (float*)sh_ref;
    __syncthreads();
    for (int i = tid; i < NB1; i += NT) fh[i] = 0.f;
    __syncthreads();
    for (u32 c = tid; c < nP; c += NT)
      atomicAdd(&fh[(cPk[c] >> 8) & 0xFFFu], wexp(cPk[c]));
    crossWt(fh, NB1, P, wbp, ftmp, s_res, s_fres, tid);
    int fA = (int)s_res[0]; u32 aP = s_res[1]; float wA = s_fres[0];
    if (!fA) { tauP = bp << 20; }         // keep whole L1 bin (rounding edge)
    else {
      __syncthreads();
      for (int i = tid; i < 512; i += NT) sh_ref[i] = 0u;  // wt[0..255]+cnt[256..511]
      __syncthreads();
      for (u32 c = tid; c < nP; c += NT)
        if (((cPk[c] >> 8) & 0xFFFu) == aP) {
          atomicAdd(&fh[cPk[c] & 0xFFu], wexp(cPk[c]));
          atomicAdd(&sh_ref[256 + (cPk[c] & 0xFFu)], 1u);
        }
      crossWt(fh, 256, P, wA, ftmp, s_res, s_fres, tid);
      int fB = (int)s_res[0]; u32 bP3 = s_res[1]; float wB = s_fres[0];
      if (!fB) { tauP = (bp << 20) | (aP << 8); }          // keep whole sub-bin
      else {
        tauP = (bp << 20) | (aP << 8) | bP3;
        u32 cntEqP = sh_ref[256 + bP3];
        float wt = wexp(tauP);
        u32 tP;
        if (wt > 0.f) {
          float r = (P - wB) / wt;        // kept ties: wB + (t-1)*wt <= P
          if (r < 0.f) r = 0.f;
          if (r >= (float)cntEqP) tP = cntEqP;
          else { tP = (u32)r + 1u; if (tP > cntEqP) tP = cntEqP; }
        } else tP = cntEqP;
        if (tP < cntEqP) {
          __syncthreads();
          for (int i = tid; i < 256; i += NT) sh_ref[i] = 0u;
          __syncthreads();
          for (u32 c = tid; c < nP; c += NT)
            if (cPk[c] == tauP) atomicAdd(&sh_ref[cPi[c] >> 8], 1u);
          crossCnt(sh_ref, 256, tP, 1, stmp, s_res, tid);
          u32 iA = s_res[0], ciA = s_res[1];
          __syncthreads();
          for (int i = tid; i < 256; i += NT) sh_ref[i] = 0u;
          __syncthreads();
          for (u32 c = tid; c < nP; c += NT)
            if (cPk[c] == tauP && (cPi[c] >> 8) == iA)
              atomicAdd(&sh_ref[cPi[c] & 0xFFu], 1u);
          crossCnt(sh_ref, 256, tP - ciA, 1, stmp, s_res, tid);
          idxP = (iA << 8) | s_res[0];
        }
      }
    }
  }

  // ---------- binding threshold = intersection of the two prefix sets ----------
  u32 tauS, idxS;
  if (tauK > tauP) { tauS = tauK; idxS = idxK; }
  else if (tauP > tauK) { tauS = tauP; idxS = idxP; }
  else { tauS = tauK; idxS = (idxK < idxP) ? idxK : idxP; }

  // ---------- Z_kept analytically: full bins above binS + kept candidates ----------
  const u32 binS = tauS >> 20;
  float z2 = 0.f;
  for (int i = tid; i < NB1; i += NT)
    if ((u32)i > binS) z2 += sh_wt[i];
  const u32* aKy = (tauS == tauK) ? cKk : cPk;
  const u32* aIx = (tauS == tauK) ? cKi : cPi;
  const u32 nS = (tauS == tauK) ? nK : nP;
  for (u32 c = tid; c < nS; c += NT) {
    u32 key = aKy[c];
    if (key > tauS || (key == tauS && aIx[c] <= idxS)) z2 += wexp(key);
  }
  const float Zk = blockSumF(z2, ftmp, tid);
  const float invZ = 1.0f / Zk;

  // ---------- P3: single fused output pass ----------
  float* outf = (float*)keys;
  auto keep = [&](u32 key, u32 e) {
    return (key > tauS || (key == tauS && e <= idxS)) ? wexp(key) * invZ : 0.f;
  };
  if ((int)tid < i0) { int e = (int)tid; outf[base + e] = keep(keys[base + e], (u32)e); }
  if ((int)tid < V - tail0) { int e = tail0 + (int)tid; outf[base + e] = keep(keys[base + e], (u32)e); }
  for (int j = (int)tid; j < Nv; j += NT) {
    int e = i0 + j * 4;
    uint4 K4 = *(const uint4*)(keys + base + e);
    float4 O;
    O.x = keep(K4.x, (u32)e);
    O.y = keep(K4.y, (u32)(e + 1));
    O.z = keep(K4.z, (u32)(e + 2));
    O.w = keep(K4.w, (u32)(e + 3));
    *(float4*)(outf + base + e) = O;
  }
}

extern "C" void kernel_launch(void* const* d_in, const int* in_sizes, int n_in,
                              void* d_out, int out_size, void* d_ws, size_t ws_size,
                              hipStream_t stream) {
  const float* logits = (const float*)d_in[0];
  const float* presp  = (const float*)d_in[1];
  const float* freqp  = (const float*)d_in[2];
  const float* tempp  = (const float*)d_in[3];
  const float* toppp  = (const float*)d_in[4];
  const int*   toks   = (const int*)d_in[5];
  const int*   topkp  = (const int*)d_in[6];

  sampler_main_kernel<<<BROWS, NT, 0, stream>>>(logits, presp, freqp, tempp, toppp,
                                                toks, topkp, (u32*)d_out);
}